// Round 4
// baseline (3099.801 us; speedup 1.0000x reference)
//
#include <hip/hip_runtime.h>
#include <hip/hip_bf16.h>
#include <stdint.h>

#define SLEN 2048
#define HIDN 4096
#define NHEAD 32
#define NKV 8
#define HD 128

typedef __hip_bfloat16 bf16;
typedef short short8 __attribute__((ext_vector_type(8)));
typedef float f32x4 __attribute__((ext_vector_type(4)));

__device__ __forceinline__ void gld16(const void* g, void* l) {
  __builtin_amdgcn_global_load_lds((const __attribute__((address_space(1))) void*)g,
                                   (__attribute__((address_space(3))) void*)l,
                                   16, 0, 0);
}

// bf16 MFMA GEMM: C[M,N] = A[M,K] * B[N,K]^T, operands K-major (B stored transposed).
// SPLIT=1: A,B are hi+lo bf16 pairs; ah*bh + ah*bl + al*bh (≈fp32 accuracy).
// OUTBF16: 1 -> bf16 C, 0 -> fp32 C.
template<int SPLIT, int OUTBF16>
__global__ __launch_bounds__(256) void gemm_kernel(
    const bf16* __restrict__ Ah, const bf16* __restrict__ Al,
    const bf16* __restrict__ Bh, const bf16* __restrict__ Bl,
    void* __restrict__ Cv, int K, int lda, int ldb, int ldc)
{
  __shared__ __align__(16) bf16 smem[(SPLIT ? 4 : 2) * 4096];
  bf16* sAh = smem;
  bf16* sBh = smem + 4096;
  bf16* sAl = SPLIT ? smem + 8192 : nullptr;
  bf16* sBl = SPLIT ? smem + 12288 : nullptr;

  const int row0 = blockIdx.y * 128;
  const int col0 = blockIdx.x * 128;
  const int tid = threadIdx.x;
  const int w = tid >> 6;
  const int lane = tid & 63;
  const int wr = w >> 1, wc = w & 1;

  f32x4 acc[4][4] = {};

  const int fr = lane & 15;
  const int fk = (lane >> 4) << 3;

  const int nk = K >> 5;
  for (int kt = 0; kt < nk; ++kt) {
    const int k0 = kt << 5;
#pragma unroll
    for (int i = 0; i < 2; ++i) {
      const int grp = (i << 2) + w;          // 8 chunk-groups of 1KB each
      const int c = grp * 64 + lane;         // 16B chunk id within the 8KB tile
      const int r = c >> 2;                  // tile row (32 bf16 = 64B = 4 chunks/row)
      const int kk = k0 + ((c & 3) << 3);
      gld16(Ah + (long)(row0 + r) * lda + kk, sAh + grp * 512);
      gld16(Bh + (long)(col0 + r) * ldb + kk, sBh + grp * 512);
      if (SPLIT) {
        gld16(Al + (long)(row0 + r) * lda + kk, sAl + grp * 512);
        gld16(Bl + (long)(col0 + r) * ldb + kk, sBl + grp * 512);
      }
    }
    __syncthreads();   // drains vmcnt -> LDS valid
    short8 a_h[4], b_h[4], a_l[4], b_l[4];
#pragma unroll
    for (int m = 0; m < 4; ++m) {
      a_h[m] = *(const short8*)(sAh + (wr * 64 + m * 16 + fr) * 32 + fk);
      b_h[m] = *(const short8*)(sBh + (wc * 64 + m * 16 + fr) * 32 + fk);
      if (SPLIT) {
        a_l[m] = *(const short8*)(sAl + (wr * 64 + m * 16 + fr) * 32 + fk);
        b_l[m] = *(const short8*)(sBl + (wc * 64 + m * 16 + fr) * 32 + fk);
      }
    }
#pragma unroll
    for (int m = 0; m < 4; ++m)
#pragma unroll
      for (int n = 0; n < 4; ++n) {
        acc[m][n] = __builtin_amdgcn_mfma_f32_16x16x32_bf16(a_h[m], b_h[n], acc[m][n], 0, 0, 0);
        if (SPLIT) {
          acc[m][n] = __builtin_amdgcn_mfma_f32_16x16x32_bf16(a_h[m], b_l[n], acc[m][n], 0, 0, 0);
          acc[m][n] = __builtin_amdgcn_mfma_f32_16x16x32_bf16(a_l[m], b_h[n], acc[m][n], 0, 0, 0);
        }
      }
    __syncthreads();
  }

  // C/D layout: col = lane&15, row = (lane>>4)*4 + reg  [m89-verified]
  const int cr = (lane >> 4) << 2;
  const int cc = lane & 15;
#pragma unroll
  for (int m = 0; m < 4; ++m)
#pragma unroll
    for (int n = 0; n < 4; ++n)
#pragma unroll
      for (int r = 0; r < 4; ++r) {
        const long row = row0 + wr * 64 + m * 16 + cr + r;
        const long col = col0 + wc * 64 + n * 16 + cc;
        if (OUTBF16)
          ((bf16*)Cv)[row * (long)ldc + col] = __float2bfloat16(acc[m][n][r]);
        else
          ((float*)Cv)[row * (long)ldc + col] = acc[m][n][r];
      }
}

// dst[n][k] = cast(src[k][n]); optional lo residual. 64x64 tiles via LDS.
__global__ __launch_bounds__(256) void transpose_split_kernel(
    const float* __restrict__ src, long srcZ, int srcLd,
    bf16* __restrict__ dh, bf16* __restrict__ dl, long dstZ, int dstLd)
{
  __shared__ float t[64][65];
  const int z = blockIdx.z;
  src += (long)z * srcZ;
  const long db = (long)z * dstZ;
  const int k0 = blockIdx.x * 64;  // src row tile
  const int n0 = blockIdx.y * 64;  // src col tile
  const int tx = threadIdx.x & 63;
  const int ty = threadIdx.x >> 6;
#pragma unroll
  for (int r = ty; r < 64; r += 4)
    t[r][tx] = src[(long)(k0 + r) * srcLd + n0 + tx];
  __syncthreads();
#pragma unroll
  for (int r = ty; r < 64; r += 4) {
    const float v = t[tx][r];
    const bf16 hv = __float2bfloat16(v);
    const long idx = db + (long)(n0 + r) * dstLd + k0 + tx;
    dh[idx] = hv;
    if (dl) dl[idx] = __float2bfloat16(v - __bfloat162float(hv));
  }
}

__global__ __launch_bounds__(256) void split_hs_kernel(
    const float* __restrict__ x, bf16* __restrict__ hi, bf16* __restrict__ lo, int n)
{
  const int i = (blockIdx.x * 256 + threadIdx.x) * 4;
  if (i >= n) return;
  const f32x4 v = *(const f32x4*)(x + i);
#pragma unroll
  for (int j = 0; j < 4; ++j) {
    const bf16 hv = __float2bfloat16(v[j]);
    hi[i + j] = hv;
    lo[i + j] = __float2bfloat16(v[j] - __bfloat162float(hv));
  }
}

// One wave per (s, head): RMSNorm over D=128 (fp32) then RoPE; writes split bf16 [head][s][d].
__global__ __launch_bounds__(256) void rope_norm_kernel(
    const float* __restrict__ x_, int ld, int nh,
    const float* __restrict__ nw, const float* __restrict__ cosb,
    const float* __restrict__ sinb, const float* __restrict__ epsp,
    bf16* __restrict__ dh, bf16* __restrict__ dl)
{
  const int gw = blockIdx.x * 4 + (threadIdx.x >> 6);
  const int lane = threadIdx.x & 63;
  const int srow = gw / nh;
  const int head = gw - srow * nh;
  const float* x = x_ + (long)srow * ld + head * HD;
  const float x0 = x[lane];
  const float x1 = x[lane + 64];
  float ss = x0 * x0 + x1 * x1;
#pragma unroll
  for (int o = 32; o > 0; o >>= 1) ss += __shfl_xor(ss, o);
  const float rr = rsqrtf(ss * (1.0f / 128.0f) + epsp[0]);
  const float nv0 = x0 * rr * nw[lane];
  const float nv1 = x1 * rr * nw[lane + 64];
  const float c0 = cosb[srow * HD + lane];
  const float c1 = cosb[srow * HD + lane + 64];
  const float sn0 = sinb[srow * HD + lane];
  const float sn1 = sinb[srow * HD + lane + 64];
  const float o0 = nv0 * c0 - nv1 * sn0;   // out[d]    = x[d]c - x[d+64]s  (d<64)
  const float o1 = nv1 * c1 + nv0 * sn1;   // out[d+64] = x[d+64]c + x[d]s
  const long base = ((long)head * SLEN + srow) * HD;
  const bf16 h0 = __float2bfloat16(o0);
  const bf16 h1 = __float2bfloat16(o1);
  dh[base + lane] = h0;
  dh[base + lane + 64] = h1;
  dl[base + lane] = __float2bfloat16(o0 - __bfloat162float(h0));
  dl[base + lane + 64] = __float2bfloat16(o1 - __bfloat162float(h1));
}

// One block per row of 2048 logits: fp32 softmax -> bf16 probs.
__global__ __launch_bounds__(256) void softmax_kernel(
    const float* __restrict__ S, bf16* __restrict__ P)
{
  const long off = (long)blockIdx.x * SLEN;
  const float* row = S + off;
  const int tid = threadIdx.x;
  float v[8];
#pragma unroll
  for (int i = 0; i < 8; ++i) v[i] = row[tid + i * 256];
  float m = v[0];
#pragma unroll
  for (int i = 1; i < 8; ++i) m = fmaxf(m, v[i]);
#pragma unroll
  for (int o = 32; o > 0; o >>= 1) m = fmaxf(m, __shfl_xor(m, o));
  __shared__ float redm[4];
  __shared__ float reds[4];
  if ((tid & 63) == 0) redm[tid >> 6] = m;
  __syncthreads();
  m = fmaxf(fmaxf(redm[0], redm[1]), fmaxf(redm[2], redm[3]));
  float sum = 0.0f;
#pragma unroll
  for (int i = 0; i < 8; ++i) { v[i] = __expf(v[i] - m); sum += v[i]; }
#pragma unroll
  for (int o = 32; o > 0; o >>= 1) sum += __shfl_xor(sum, o);
  if ((tid & 63) == 0) reds[tid >> 6] = sum;
  __syncthreads();
  sum = reds[0] + reds[1] + reds[2] + reds[3];
  const float inv = 1.0f / sum;
  bf16* p = P + off;
#pragma unroll
  for (int i = 0; i < 8; ++i) p[tid + i * 256] = __float2bfloat16(v[i] * inv);
}

extern "C" void kernel_launch(void* const* d_in, const int* in_sizes, int n_in,
                              void* d_out, int out_size, void* d_ws, size_t ws_size,
                              hipStream_t stream)
{
  // Inputs are fp32 (established round 3: fp32 reads don't fault; bf16 reads NaN).
  const float* hs   = (const float*)d_in[0];
  const float* cosb = (const float*)d_in[1];
  const float* sinb = (const float*)d_in[2];
  const float* wq   = (const float*)d_in[3];
  const float* wk   = (const float*)d_in[4];
  const float* wv   = (const float*)d_in[5];
  const float* wo   = (const float*)d_in[6];
  const float* qw   = (const float*)d_in[7];
  const float* kw   = (const float*)d_in[8];
  const float* eps  = (const float*)d_in[9];

  // ---- workspace layout (116 MiB peak, offsets in bytes) ----
  const size_t MB = 1024 * 1024;
  if (ws_size < 116 * MB) return;  // round-2 ran within this budget
  uint8_t* ws = (uint8_t*)d_ws;

  bf16*  hsh  = (bf16*)(ws + 0 * MB);     // [2048][4096] hi        16 MiB
  bf16*  hsl  = (bf16*)(ws + 16 * MB);    // [2048][4096] lo        16 MiB
  bf16*  qh   = (bf16*)(ws + 32 * MB);    // [32][2048][128]        16 MiB
  bf16*  ql   = (bf16*)(ws + 48 * MB);    //                        16 MiB
  bf16*  kh   = (bf16*)(ws + 64 * MB);    // [8][2048][128]          4 MiB
  bf16*  kl   = (bf16*)(ws + 68 * MB);    //                         4 MiB
  bf16*  Vt   = (bf16*)(ws + 72 * MB);    // [8][128][2048]          4 MiB
  bf16*  AO   = (bf16*)(ws + 76 * MB);    // [2048][4096]           16 MiB
  bf16*  Wch  = (bf16*)(ws + 92 * MB);    // [1024][4096] chunk hi   8 MiB
  bf16*  Wcl  = (bf16*)(ws + 100 * MB);   // chunk lo                8 MiB
  float* Cf32 = (float*)(ws + 108 * MB);  // [2048][1024] f32        8 MiB
  // attention-phase aliases (weight staging dead by then):
  float* Plog = (float*)(ws + 92 * MB);   // [2048][2048] f32       16 MiB (over Wch/Wcl)
  bf16*  Pb   = (bf16*)(ws + 108 * MB);   // [2048][2048] bf16       8 MiB (over Cf32)
  bf16*  WoT  = (bf16*)(ws + 0 * MB);     // [4096][4096] bf16      32 MiB (over hsh/hsl, dead after projections)

  // 1) split hidden_states to bf16 hi/lo
  split_hs_kernel<<<SLEN * HIDN / 4 / 256, 256, 0, stream>>>(hs, hsh, hsl, SLEN * HIDN);

  // 2) Q projection in 4 chunks of 8 heads (1024 cols each)
  for (int c = 0; c < 4; ++c) {
    transpose_split_kernel<<<dim3(64, 16, 1), 256, 0, stream>>>(
        wq + c * 1024, 0, HIDN, Wch, Wcl, 0, HIDN);
    gemm_kernel<1, 0><<<dim3(8, 16, 1), 256, 0, stream>>>(
        hsh, hsl, Wch, Wcl, (void*)Cf32, HIDN, HIDN, HIDN, 1024);
    rope_norm_kernel<<<SLEN * 8 / 4, 256, 0, stream>>>(
        Cf32, 1024, 8, qw, cosb, sinb, eps,
        qh + (size_t)c * 8 * SLEN * HD, ql + (size_t)c * 8 * SLEN * HD);
  }

  // 3) K projection (1024 cols)
  transpose_split_kernel<<<dim3(64, 16, 1), 256, 0, stream>>>(
      wk, 0, 1024, Wch, Wcl, 0, HIDN);
  gemm_kernel<1, 0><<<dim3(8, 16, 1), 256, 0, stream>>>(
      hsh, hsl, Wch, Wcl, (void*)Cf32, HIDN, HIDN, HIDN, 1024);
  rope_norm_kernel<<<SLEN * 8 / 4, 256, 0, stream>>>(
      Cf32, 1024, 8, kw, cosb, sinb, eps, kh, kl);

  // 4) V projection (plain bf16), then per-head transpose -> Vt [kvh][d][s]
  transpose_split_kernel<<<dim3(64, 16, 1), 256, 0, stream>>>(
      wv, 0, 1024, Wch, nullptr, 0, HIDN);
  gemm_kernel<0, 0><<<dim3(8, 16, 1), 256, 0, stream>>>(
      hsh, nullptr, Wch, nullptr, (void*)Cf32, HIDN, HIDN, HIDN, 1024);
  transpose_split_kernel<<<dim3(32, 2, 8), 256, 0, stream>>>(
      Cf32, 128, 1024, Vt, nullptr, (long)HD * SLEN, SLEN);

  // 5) wo^T -> WoT (hsh/hsl dead after step 4)
  transpose_split_kernel<<<dim3(64, 64, 1), 256, 0, stream>>>(
      wo, 0, HIDN, WoT, nullptr, 0, HIDN);

  // 6) attention, one head at a time (Plog/Pb reused; split-bf16 logits ≈ fp32 accurate)
  for (int h = 0; h < NHEAD; ++h) {
    const size_t kvOff = (size_t)(h / 4) * SLEN * HD;
    gemm_kernel<1, 0><<<dim3(16, 16, 1), 256, 0, stream>>>(
        qh + (size_t)h * SLEN * HD, ql + (size_t)h * SLEN * HD,
        kh + kvOff, kl + kvOff, (void*)Plog, HD, HD, HD, SLEN);
    softmax_kernel<<<SLEN, 256, 0, stream>>>(Plog, Pb);
    gemm_kernel<0, 1><<<dim3(1, 16, 1), 256, 0, stream>>>(
        Pb, nullptr, Vt + (size_t)(h / 4) * HD * SLEN, nullptr,
        (void*)(AO + (size_t)h * HD), SLEN, SLEN, SLEN, HIDN);
  }

  // 7) output projection -> FP32 d_out (the round-2 bug: was bf16)
  gemm_kernel<0, 0><<<dim3(32, 16, 1), 256, 0, stream>>>(
      AO, nullptr, WoT, nullptr, d_out, HIDN, HIDN, HIDN, HIDN);
}

// Round 5
// 569.004 us; speedup vs baseline: 5.4478x; 5.4478x over previous
//
#include <hip/hip_runtime.h>
#include <hip/hip_bf16.h>
#include <stdint.h>

#define SLEN 2048
#define HIDN 4096
#define NHEAD 32
#define NKV 8
#define HD 128
#define QKV_N 6144

typedef __hip_bfloat16 bf16;
typedef short short8 __attribute__((ext_vector_type(8)));
typedef float f32x4 __attribute__((ext_vector_type(4)));

__device__ __forceinline__ void gld16(const void* g, void* l) {
  __builtin_amdgcn_global_load_lds((const __attribute__((address_space(1))) void*)g,
                                   (__attribute__((address_space(3))) void*)l,
                                   16, 0, 0);
}

// Read a short8 from a [*][128] bf16 LDS tile whose 16B slots are XOR-swizzled
// within each row: elem ^= (row&7)<<3  (slot ^= row&7). 2-way banks max.
__device__ __forceinline__ short8 ldswz(const bf16* s, int row, int elem) {
  return *(const short8*)(s + row * 128 + (elem ^ ((row & 7) << 3)));
}

// Plain bf16 MFMA GEMM: C[M,N](fp32) = A[M,K] * B[N,K]^T, K-major operands.
// 128x128 tile, 4 waves, XCD-swizzled block ids.
__global__ __launch_bounds__(256) void gemm_kernel(
    const bf16* __restrict__ A, const bf16* __restrict__ B,
    float* __restrict__ C, int K, int lda, int ldb, int ldc)
{
  __shared__ __align__(16) bf16 smem[2 * 4096];
  bf16* sA = smem;
  bf16* sB = smem + 4096;

  const int nwg = gridDim.x * gridDim.y;
  int bid = blockIdx.y * gridDim.x + blockIdx.x;
  { // bijective 8-XCD chunked remap (m204)
    const int q = nwg >> 3, rr = nwg & 7, x = bid & 7, idx = bid >> 3;
    bid = (x < rr ? x * (q + 1) : rr * (q + 1) + (x - rr) * q) + idx;
  }
  const int bx = bid % gridDim.x;
  const int by = bid / gridDim.x;
  const int row0 = by * 128;
  const int col0 = bx * 128;

  const int tid = threadIdx.x;
  const int w = tid >> 6;
  const int lane = tid & 63;
  const int wr = w >> 1, wc = w & 1;

  f32x4 acc[4][4] = {};

  const int fr = lane & 15;
  const int fk = (lane >> 4) << 3;

  const int nk = K >> 5;
  for (int kt = 0; kt < nk; ++kt) {
    const int k0 = kt << 5;
#pragma unroll
    for (int i = 0; i < 2; ++i) {
      const int grp = (i << 2) + w;          // 8 chunk-groups of 1KB each
      const int c = grp * 64 + lane;         // 16B chunk id within the 8KB tile
      const int r = c >> 2;                  // tile row (32 bf16 = 64B = 4 chunks/row)
      const int kk = k0 + ((c & 3) << 3);
      gld16(A + (long)(row0 + r) * lda + kk, sA + grp * 512);
      gld16(B + (long)(col0 + r) * ldb + kk, sB + grp * 512);
    }
    __syncthreads();   // drains vmcnt -> LDS valid
    short8 a[4], b[4];
#pragma unroll
    for (int m = 0; m < 4; ++m) {
      a[m] = *(const short8*)(sA + (wr * 64 + m * 16 + fr) * 32 + fk);
      b[m] = *(const short8*)(sB + (wc * 64 + m * 16 + fr) * 32 + fk);
    }
#pragma unroll
    for (int m = 0; m < 4; ++m)
#pragma unroll
      for (int n = 0; n < 4; ++n)
        acc[m][n] = __builtin_amdgcn_mfma_f32_16x16x32_bf16(a[m], b[n], acc[m][n], 0, 0, 0);
    __syncthreads();
  }

  const int cr = (lane >> 4) << 2;
  const int cc = lane & 15;
#pragma unroll
  for (int m = 0; m < 4; ++m)
#pragma unroll
    for (int n = 0; n < 4; ++n)
#pragma unroll
      for (int r = 0; r < 4; ++r) {
        const long row = row0 + wr * 64 + m * 16 + cr + r;
        const long col = col0 + wc * 64 + n * 16 + cc;
        C[row * (long)ldc + col] = acc[m][n][r];
      }
}

// dst[z][n][k] = bf16(src[z][k][n]), fp32 src. 64x64 tiles via LDS.
__global__ __launch_bounds__(256) void transpose_kernel(
    const float* __restrict__ src, long srcZ, int srcLd,
    bf16* __restrict__ dst, long dstZ, int dstLd)
{
  __shared__ float t[64][65];
  const int z = blockIdx.z;
  src += (long)z * srcZ;
  const long db = (long)z * dstZ;
  const int k0 = blockIdx.x * 64;
  const int n0 = blockIdx.y * 64;
  const int tx = threadIdx.x & 63;
  const int ty = threadIdx.x >> 6;
#pragma unroll
  for (int r = ty; r < 64; r += 4)
    t[r][tx] = src[(long)(k0 + r) * srcLd + n0 + tx];
  __syncthreads();
#pragma unroll
  for (int r = ty; r < 64; r += 4)
    dst[db + (long)(n0 + r) * dstLd + k0 + tx] = __float2bfloat16(t[tx][r]);
}

__global__ __launch_bounds__(256) void cvt_bf16_kernel(
    const float* __restrict__ x, bf16* __restrict__ y, int n)
{
  const int i = (blockIdx.x * 256 + threadIdx.x) * 4;
  if (i >= n) return;
  const f32x4 v = *(const f32x4*)(x + i);
#pragma unroll
  for (int j = 0; j < 4; ++j) y[i + j] = __float2bfloat16(v[j]);
}

// One wave per (s, head): RMSNorm over D=128 (fp32) then RoPE; split hi/lo bf16 out [head][s][d].
__global__ __launch_bounds__(256) void rope_norm_kernel(
    const float* __restrict__ x_, int ld, int nh,
    const float* __restrict__ nw, const float* __restrict__ cosb,
    const float* __restrict__ sinb, const float* __restrict__ epsp,
    bf16* __restrict__ dh, bf16* __restrict__ dl)
{
  const int gw = blockIdx.x * 4 + (threadIdx.x >> 6);
  const int lane = threadIdx.x & 63;
  const int srow = gw / nh;
  const int head = gw - srow * nh;
  const float* x = x_ + (long)srow * ld + head * HD;
  const float x0 = x[lane];
  const float x1 = x[lane + 64];
  float ss = x0 * x0 + x1 * x1;
#pragma unroll
  for (int o = 32; o > 0; o >>= 1) ss += __shfl_xor(ss, o);
  const float rr = rsqrtf(ss * (1.0f / 128.0f) + epsp[0]);
  const float nv0 = x0 * rr * nw[lane];
  const float nv1 = x1 * rr * nw[lane + 64];
  const float c0 = cosb[srow * HD + lane];
  const float c1 = cosb[srow * HD + lane + 64];
  const float sn0 = sinb[srow * HD + lane];
  const float sn1 = sinb[srow * HD + lane + 64];
  const float o0 = nv0 * c0 - nv1 * sn0;
  const float o1 = nv1 * c1 + nv0 * sn1;
  const long base = ((long)head * SLEN + srow) * HD;
  const bf16 h0 = __float2bfloat16(o0);
  const bf16 h1 = __float2bfloat16(o1);
  dh[base + lane] = h0;
  dh[base + lane + 64] = h1;
  dl[base + lane] = __float2bfloat16(o0 - __bfloat162float(h0));
  dl[base + lane + 64] = __float2bfloat16(o1 - __bfloat162float(h1));
}

// Flash attention: one block = (q-tile of 128 rows, head). 4 waves; wave w owns
// q rows [w*32, w*32+32) x all 128 keys of each K-tile (row stats wave-local).
// QK^T is split-bf16 (hi/lo) for ~fp32 logits; V/P plain bf16.
__global__ __launch_bounds__(256, 1) void flash_kernel(
    const bf16* __restrict__ qh, const bf16* __restrict__ ql,
    const bf16* __restrict__ kh, const bf16* __restrict__ kl,
    const bf16* __restrict__ vt,   // [kvh][d=128][s=2048]
    bf16* __restrict__ AO)         // [2048][4096]
{
  __shared__ __align__(16) bf16 sKh[128 * 128];
  __shared__ __align__(16) bf16 sKl[128 * 128];
  __shared__ __align__(16) bf16 sV[128 * 128];     // [d][s-chunk]
  __shared__ __align__(16) bf16 sP[4 * 32 * 128];  // per-wave 32x128

  const int qt = blockIdx.x;
  const int head = blockIdx.y;
  const int kvh = head >> 2;
  const int tid = threadIdx.x;
  const int w = tid >> 6;
  const int lane = tid & 63;
  const int fr = lane & 15;
  const int g = lane >> 4;
  const int fk = g << 3;

  // Q fragments in registers (A-layout: row=fr, k=ks*32+fk..+7), rows w*32+m*16+fr
  short8 aqh[2][4], aql[2][4];
  {
    const long qb = ((long)head * SLEN + qt * 128 + w * 32 + fr) * HD + fk;
#pragma unroll
    for (int m = 0; m < 2; ++m)
#pragma unroll
      for (int ks = 0; ks < 4; ++ks) {
        aqh[m][ks] = *(const short8*)(qh + qb + m * 16 * HD + ks * 32);
        aql[m][ks] = *(const short8*)(ql + qb + m * 16 * HD + ks * 32);
      }
  }

  f32x4 o[2][8] = {};
  float mrow[2][4], lrow[2][4];
#pragma unroll
  for (int m = 0; m < 2; ++m)
#pragma unroll
    for (int r = 0; r < 4; ++r) { mrow[m][r] = -3.0e38f; lrow[m][r] = 0.0f; }

  bf16* sPw = sP + w * 32 * 128;
  const bf16* kbh = kh + (long)kvh * SLEN * HD;
  const bf16* kbl = kl + (long)kvh * SLEN * HD;
  const bf16* vb = vt + (long)kvh * HD * SLEN;

  for (int t = 0; t < SLEN / 128; ++t) {
    // stage K hi/lo [key][d] and V [d][s] tiles; source pre-swizzled so a
    // swizzled read sees logical data (gld16 writes linearly; rule 21)
#pragma unroll
    for (int i = 0; i < 8; ++i) {
      const int c = i * 256 + tid;
      const int row = c >> 4;
      const int slot = (c & 15) ^ (row & 7);
      const int dstE = (i * 256 + w * 64) * 8;  // wave-uniform dest
      gld16(kbh + (long)(t * 128 + row) * HD + slot * 8, sKh + dstE);
      gld16(kbl + (long)(t * 128 + row) * HD + slot * 8, sKl + dstE);
      gld16(vb + (long)row * SLEN + t * 128 + slot * 8, sV + dstE);
    }
    __syncthreads();

    // S = Q K^T (split: qh*kh + qh*kl + ql*kh)
    f32x4 s[2][8] = {};
#pragma unroll
    for (int n = 0; n < 8; ++n) {
      short8 bh[4], bl[4];
#pragma unroll
      for (int ks = 0; ks < 4; ++ks) {
        bh[ks] = ldswz(sKh, n * 16 + fr, ks * 32 + fk);
        bl[ks] = ldswz(sKl, n * 16 + fr, ks * 32 + fk);
      }
#pragma unroll
      for (int m = 0; m < 2; ++m)
#pragma unroll
        for (int ks = 0; ks < 4; ++ks) {
          s[m][n] = __builtin_amdgcn_mfma_f32_16x16x32_bf16(aqh[m][ks], bh[ks], s[m][n], 0, 0, 0);
          s[m][n] = __builtin_amdgcn_mfma_f32_16x16x32_bf16(aqh[m][ks], bl[ks], s[m][n], 0, 0, 0);
          s[m][n] = __builtin_amdgcn_mfma_f32_16x16x32_bf16(aql[m][ks], bh[ks], s[m][n], 0, 0, 0);
        }
    }

    // online softmax; lane owns rows m*16+g*4+r, cols n*16+fr (16-lane row groups)
#pragma unroll
    for (int m = 0; m < 2; ++m)
#pragma unroll
      for (int r = 0; r < 4; ++r) {
        float mx = s[m][0][r];
#pragma unroll
        for (int n = 1; n < 8; ++n) mx = fmaxf(mx, s[m][n][r]);
        mx = fmaxf(mx, __shfl_xor(mx, 1));
        mx = fmaxf(mx, __shfl_xor(mx, 2));
        mx = fmaxf(mx, __shfl_xor(mx, 4));
        mx = fmaxf(mx, __shfl_xor(mx, 8));
        const float mnew = fmaxf(mrow[m][r], mx);
        const float corr = __expf(mrow[m][r] - mnew);
        mrow[m][r] = mnew;
        float ps = 0.0f;
#pragma unroll
        for (int n = 0; n < 8; ++n) {
          const float p = __expf(s[m][n][r] - mnew);
          s[m][n][r] = p;
          ps += p;
        }
        ps += __shfl_xor(ps, 1);
        ps += __shfl_xor(ps, 2);
        ps += __shfl_xor(ps, 4);
        ps += __shfl_xor(ps, 8);
        lrow[m][r] = lrow[m][r] * corr + ps;
#pragma unroll
        for (int n = 0; n < 8; ++n) o[m][n][r] *= corr;
      }

    // P -> per-wave LDS (bf16, swizzled) to transpose C-layout into A-layout
#pragma unroll
    for (int m = 0; m < 2; ++m)
#pragma unroll
      for (int r = 0; r < 4; ++r) {
        const int qr = m * 16 + g * 4 + r;
#pragma unroll
        for (int n = 0; n < 8; ++n) {
          const int col = n * 16 + fr;
          sPw[qr * 128 + (col ^ ((qr & 7) << 3))] = __float2bfloat16(s[m][n][r]);
        }
      }
    // same-wave LDS RAW; compiler inserts lgkm waits

    // O += P V
    short8 pa[2][4];
#pragma unroll
    for (int m = 0; m < 2; ++m)
#pragma unroll
      for (int ks = 0; ks < 4; ++ks)
        pa[m][ks] = ldswz(sPw, m * 16 + fr, ks * 32 + fk);
#pragma unroll
    for (int n = 0; n < 8; ++n) {
      short8 bv[4];
#pragma unroll
      for (int ks = 0; ks < 4; ++ks)
        bv[ks] = ldswz(sV, n * 16 + fr, ks * 32 + fk);
#pragma unroll
      for (int m = 0; m < 2; ++m)
#pragma unroll
        for (int ks = 0; ks < 4; ++ks)
          o[m][n] = __builtin_amdgcn_mfma_f32_16x16x32_bf16(pa[m][ks], bv[ks], o[m][n], 0, 0, 0);
    }
    __syncthreads();
  }

#pragma unroll
  for (int m = 0; m < 2; ++m)
#pragma unroll
    for (int r = 0; r < 4; ++r) {
      const float inv = 1.0f / lrow[m][r];
      const long row = qt * 128 + w * 32 + m * 16 + g * 4 + r;
#pragma unroll
      for (int n = 0; n < 8; ++n)
        AO[row * HIDN + head * 128 + n * 16 + fr] = __float2bfloat16(o[m][n][r] * inv);
    }
}

extern "C" void kernel_launch(void* const* d_in, const int* in_sizes, int n_in,
                              void* d_out, int out_size, void* d_ws, size_t ws_size,
                              hipStream_t stream)
{
  const float* hs   = (const float*)d_in[0];
  const float* cosb = (const float*)d_in[1];
  const float* sinb = (const float*)d_in[2];
  const float* wq   = (const float*)d_in[3];
  const float* wk   = (const float*)d_in[4];
  const float* wv   = (const float*)d_in[5];
  const float* wo   = (const float*)d_in[6];
  const float* qw   = (const float*)d_in[7];
  const float* kw   = (const float*)d_in[8];
  const float* eps  = (const float*)d_in[9];

  const size_t MB = 1024 * 1024;
  if (ws_size < 116 * MB) return;  // known-good budget (rounds 2/4)
  uint8_t* ws = (uint8_t*)d_ws;

  // phase-1 layout:
  bf16*  hsb = (bf16*)(ws + 0 * MB);    // [2048][4096]          16 MiB
  bf16*  WT  = (bf16*)(ws + 16 * MB);   // [6144][4096]          48 MiB
  float* QKV = (float*)(ws + 64 * MB);  // [2048][6144] f32      48 MiB
  // phase-2 (WT dead after QKV GEMM):
  bf16*  qh = (bf16*)(ws + 16 * MB);    // [32][2048][128]       16 MiB
  bf16*  ql = (bf16*)(ws + 32 * MB);    //                       16 MiB
  bf16*  kh = (bf16*)(ws + 48 * MB);    // [8][2048][128]         4 MiB
  bf16*  kl = (bf16*)(ws + 52 * MB);    //                        4 MiB
  bf16*  Vt = (bf16*)(ws + 56 * MB);    // [8][128][2048]         4 MiB
  // phase-3 (QKV dead after rope/V-transpose):
  bf16*  AO  = (bf16*)(ws + 64 * MB);   // [2048][4096]          16 MiB
  bf16*  WoT = (bf16*)(ws + 80 * MB);   // [4096][4096]          32 MiB  (peak 112 MiB)

  // 1) hs -> bf16
  cvt_bf16_kernel<<<SLEN * HIDN / 4 / 256, 256, 0, stream>>>(hs, hsb, SLEN * HIDN);

  // 2) fused weight transpose: WT[n][k] = w*[k][n] for n in [Q|K|V]
  transpose_kernel<<<dim3(64, 64, 1), 256, 0, stream>>>(wq, 0, HIDN, WT, 0, HIDN);
  transpose_kernel<<<dim3(64, 16, 1), 256, 0, stream>>>(wk, 0, 1024, WT + (size_t)4096 * HIDN, 0, HIDN);
  transpose_kernel<<<dim3(64, 16, 1), 256, 0, stream>>>(wv, 0, 1024, WT + (size_t)5120 * HIDN, 0, HIDN);

  // 3) one fused QKV projection GEMM (768 blocks)
  gemm_kernel<<<dim3(48, 16, 1), 256, 0, stream>>>(hsb, WT, QKV, HIDN, HIDN, HIDN, QKV_N);

  // 4) RMSNorm + RoPE -> split hi/lo per-head layouts
  rope_norm_kernel<<<SLEN * NHEAD / 4, 256, 0, stream>>>(QKV, QKV_N, NHEAD, qw, cosb, sinb, eps, qh, ql);
  rope_norm_kernel<<<SLEN * NKV / 4, 256, 0, stream>>>(QKV + 4096, QKV_N, NKV, kw, cosb, sinb, eps, kh, kl);

  // 5) V^T per kv head: QKV[s][5120+kvh*128+d] -> Vt[kvh][d][s]
  transpose_kernel<<<dim3(32, 2, 8), 256, 0, stream>>>(QKV + 5120, 128, QKV_N, Vt, (long)HD * SLEN, SLEN);

  // 6) wo^T (QKV region dead now)
  transpose_kernel<<<dim3(64, 64, 1), 256, 0, stream>>>(wo, 0, HIDN, WoT, 0, HIDN);

  // 7) flash attention (512 blocks)
  flash_kernel<<<dim3(16, 32, 1), 256, 0, stream>>>(qh, ql, kh, kl, Vt, AO);

  // 8) output projection -> fp32 d_out (512 blocks)
  gemm_kernel<<<dim3(32, 16, 1), 256, 0, stream>>>(AO, WoT, (float*)d_out, HIDN, HIDN, HIDN, HIDN);
}